// Round 1
// baseline (2732.468 us; speedup 1.0000x reference)
//
#include <hip/hip_runtime.h>
#include <cstddef>

// LfExpert: flow block + MoE. fp32 baseline, fused epilogues.
// B=8, C=64 (per stream), E=4, K=2, HW=128.

#define HWD 128
#define HW2 16384

enum { M_PLAIN = 0, M_ADD2 = 1, M_SIGEXP = 2, M_COUPLE = 3, M_LRELU = 4, M_EACC = 5 };

__device__ __forceinline__ float wredsum(float v) {
#pragma unroll
  for (int o = 32; o > 0; o >>= 1) v += __shfl_down(v, o, 64);
  return v;
}
__device__ __forceinline__ float wredmax(float v) {
#pragma unroll
  for (int o = 32; o > 0; o >>= 1) v = fmaxf(v, __shfl_down(v, o, 64));
  return v;
}

__global__ void zero_kernel(float* __restrict__ p, int n) {
  int i0 = blockIdx.x * blockDim.x + threadIdx.x;
  int st = gridDim.x * blockDim.x;
  int n4 = n >> 2;
  for (int i = i0; i < n4; i += st) ((float4*)p)[i] = make_float4(0.f, 0.f, 0.f, 0.f);
  if (i0 == 0) {
    for (int i = n4 << 2; i < n; ++i) p[i] = 0.f;
  }
}

// ---------------- z = winv (128x128) applied as 1x1 conv on x (8,128,128,128) ----------------
__global__ __launch_bounds__(256) void mm128_kernel(const float* __restrict__ x,
                                                    const float* __restrict__ winv,
                                                    float* __restrict__ z) {
  int b = blockIdx.y;
  int p0 = blockIdx.x << 7;  // 128 pixels / block
  int t = threadIdx.x;
  int og = t >> 6;   // 0..3 -> o base og*32 (wave-uniform)
  int q = t & 63;    // pixel pair 2q, 2q+1
  __shared__ float wl[32][128];
  __shared__ float xl[32][128];
  float acc0[32] = {}, acc1[32] = {};
  for (int i0 = 0; i0 < 128; i0 += 32) {
    __syncthreads();
    for (int i = t; i < 4096; i += 256) {
      int il = i >> 7, o = i & 127;
      wl[il][o] = winv[o * 128 + i0 + il];
    }
    for (int i = t; i < 4096; i += 256) {
      int il = i >> 7, pl = i & 127;
      xl[il][pl] = x[(((size_t)b * 128 + i0 + il) << 14) + p0 + pl];
    }
    __syncthreads();
    for (int il = 0; il < 32; ++il) {
      float2 v = *(const float2*)&xl[il][q << 1];
      const float* wp = &wl[il][og << 5];
#pragma unroll
      for (int j = 0; j < 8; ++j) {
        float4 w4 = *(const float4*)(wp + (j << 2));
        acc0[j * 4 + 0] += v.x * w4.x; acc0[j * 4 + 1] += v.x * w4.y;
        acc0[j * 4 + 2] += v.x * w4.z; acc0[j * 4 + 3] += v.x * w4.w;
        acc1[j * 4 + 0] += v.y * w4.x; acc1[j * 4 + 1] += v.y * w4.y;
        acc1[j * 4 + 2] += v.y * w4.z; acc1[j * 4 + 3] += v.y * w4.w;
      }
    }
  }
#pragma unroll
  for (int j = 0; j < 32; ++j) {
    int o = (og << 5) + j;
    *(float2*)&z[(((size_t)b * 128 + o) << 14) + p0 + (q << 1)] = make_float2(acc0[j], acc1[j]);
  }
}

// ---------------- xf = fuse_w (64x128) over [y1;y2] + fuse_b ----------------
__global__ __launch_bounds__(256) void fuse_kernel(const float* __restrict__ y1,
                                                   const float* __restrict__ y2,
                                                   const float* __restrict__ fw,
                                                   const float* __restrict__ fb,
                                                   float* __restrict__ xf) {
  int b = blockIdx.y;
  int p0 = blockIdx.x << 8;  // 256 pixels / block
  int t = threadIdx.x;
  int og = t >> 7;  // 0..1
  int q = t & 127;  // pixel pair
  __shared__ float wl[32][64];
  __shared__ float xl[32][256];
  float acc0[32] = {}, acc1[32] = {};
  for (int i0 = 0; i0 < 128; i0 += 32) {
    const float* src = (i0 < 64) ? y1 : y2;
    int cb = i0 & 63;
    __syncthreads();
    for (int i = t; i < 2048; i += 256) {
      int il = i >> 6, o = i & 63;
      wl[il][o] = fw[o * 128 + i0 + il];
    }
    for (int i = t; i < 8192; i += 256) {
      int il = i >> 8, pl = i & 255;
      xl[il][pl] = src[(((size_t)b * 64 + cb + il) << 14) + p0 + pl];
    }
    __syncthreads();
    for (int il = 0; il < 32; ++il) {
      float2 v = *(const float2*)&xl[il][q << 1];
      const float* wp = &wl[il][og << 5];
#pragma unroll
      for (int j = 0; j < 8; ++j) {
        float4 w4 = *(const float4*)(wp + (j << 2));
        acc0[j * 4 + 0] += v.x * w4.x; acc0[j * 4 + 1] += v.x * w4.y;
        acc0[j * 4 + 2] += v.x * w4.z; acc0[j * 4 + 3] += v.x * w4.w;
        acc1[j * 4 + 0] += v.y * w4.x; acc1[j * 4 + 1] += v.y * w4.y;
        acc1[j * 4 + 2] += v.y * w4.z; acc1[j * 4 + 3] += v.y * w4.w;
      }
    }
  }
#pragma unroll
  for (int j = 0; j < 32; ++j) {
    int o = (og << 5) + j;
    float bo = fb[o];
    *(float2*)&xf[(((size_t)b * 64 + o) << 14) + p0 + (q << 1)] =
        make_float2(acc0[j] + bo, acc1[j] + bo);
  }
}

// ---------------- generic 3x3 conv, 64->64 ch, pad 1, fused epilogues ----------------
// in + ((b*ibs + ci)<<14); out likewise with obs; residual ptrs r1/r2/mul with their strides.
template <int MODE>
__global__ __launch_bounds__(256) void conv3x3_kernel(
    const float* __restrict__ in, int ibs, const float* __restrict__ wgt,
    const float* __restrict__ bias, float* __restrict__ out, int obs,
    const float* __restrict__ r1, int r1s, const float* __restrict__ r2, int r2s,
    const float* __restrict__ mul, int muls, const float* __restrict__ cof, int expert) {
  int b = blockIdx.y;
  float cv = 0.f;
  if (MODE == M_LRELU || MODE == M_EACC) {
    cv = cof[b * 4 + expert];
    if (cv == 0.f) return;  // block-uniform: whole expert skipped for this batch
  }
  int tile = blockIdx.x;
  int ty0 = (tile >> 3) << 4;
  int tx0 = (tile & 7) << 4;
  int t = threadIdx.x;
  int og = t >> 7;          // 0..1 (wave-uniform)
  int q = t & 127;
  int py = q >> 3;          // 0..15
  int px = (q & 7) << 1;    // 0..14 even

  __shared__ float ils[16][18][18];
  __shared__ float wls[16][9][64];

  float acc0[32] = {}, acc1[32] = {};

  for (int ci0 = 0; ci0 < 64; ci0 += 16) {
    __syncthreads();
    for (int i = t; i < 5184; i += 256) {
      int cl = i / 324; int r = i - cl * 324;
      int y = r / 18;   int xx = r - y * 18;
      int gy = ty0 + y - 1, gx = tx0 + xx - 1;
      float v = 0.f;
      if ((unsigned)gy < 128u && (unsigned)gx < 128u)
        v = in[(((size_t)b * ibs + ci0 + cl) << 14) + (gy << 7) + gx];
      ils[cl][y][xx] = v;
    }
    for (int i = t; i < 9216; i += 256) {
      int co = i / 144; int r = i - co * 144;
      wls[r / 9][r % 9][co] = wgt[co * 576 + ci0 * 9 + r];
    }
    __syncthreads();
    for (int cl = 0; cl < 16; ++cl) {
#pragma unroll
      for (int ky = 0; ky < 3; ++ky) {
        float2 va = *(const float2*)&ils[cl][py + ky][px];
        float2 vb = *(const float2*)&ils[cl][py + ky][px + 2];
        float iv[4] = {va.x, va.y, vb.x, vb.y};
#pragma unroll
        for (int kx = 0; kx < 3; ++kx) {
          float v0 = iv[kx], v1 = iv[kx + 1];
          const float* wp = &wls[cl][ky * 3 + kx][og << 5];
#pragma unroll
          for (int j = 0; j < 8; ++j) {
            float4 w4 = *(const float4*)(wp + (j << 2));
            acc0[j * 4 + 0] += v0 * w4.x; acc0[j * 4 + 1] += v0 * w4.y;
            acc0[j * 4 + 2] += v0 * w4.z; acc0[j * 4 + 3] += v0 * w4.w;
            acc1[j * 4 + 0] += v1 * w4.x; acc1[j * 4 + 1] += v1 * w4.y;
            acc1[j * 4 + 2] += v1 * w4.z; acc1[j * 4 + 3] += v1 * w4.w;
          }
        }
      }
    }
  }

  int gy = ty0 + py, gx = tx0 + px;
  int pix = (gy << 7) + gx;
#pragma unroll
  for (int j = 0; j < 32; ++j) {
    int co = (og << 5) + j;
    float bco = bias[co];
    float a0 = acc0[j] + bco, a1 = acc1[j] + bco;
    size_t oi = (((size_t)b * obs + co) << 14) + pix;
    if (MODE == M_PLAIN) {
      *(float2*)&out[oi] = make_float2(a0, a1);
    } else if (MODE == M_ADD2) {
      float2 u = *(const float2*)&r1[(((size_t)b * r1s + co) << 14) + pix];
      float2 w = *(const float2*)&r2[(((size_t)b * r2s + co) << 14) + pix];
      *(float2*)&out[oi] = make_float2(a0 + u.x + w.x, a1 + u.y + w.y);
    } else if (MODE == M_SIGEXP) {
      float2 u = *(const float2*)&r1[(((size_t)b * r1s + co) << 14) + pix];
      float t0 = a0 + u.x, t1 = a1 + u.y;
      float s0 = 1.f / (1.f + expf(-t0));
      float s1 = 1.f / (1.f + expf(-t1));
      *(float2*)&out[oi] = make_float2(expf(0.8f * (2.f * s0 - 1.f)),
                                       expf(0.8f * (2.f * s1 - 1.f)));
    } else if (MODE == M_COUPLE) {
      float2 u = *(const float2*)&r1[(((size_t)b * r1s + co) << 14) + pix];
      float2 w = *(const float2*)&r2[(((size_t)b * r2s + co) << 14) + pix];
      float2 m = *(const float2*)&mul[(((size_t)b * muls + co) << 14) + pix];
      *(float2*)&out[oi] = make_float2(a0 + u.x + w.x * m.x, a1 + u.y + w.y * m.y);
    } else if (MODE == M_LRELU) {
      float o0 = a0 > 0.f ? a0 : 0.2f * a0;
      float o1 = a1 > 0.f ? a1 : 0.2f * a1;
      *(float2*)&out[oi] = make_float2(o0, o1);
    } else if (MODE == M_EACC) {
      float2 u = *(const float2*)&r1[(((size_t)b * r1s + co) << 14) + pix];  // xf
      float2 cur = *(const float2*)&out[oi];
      *(float2*)&out[oi] = make_float2(cur.x + cv * (a0 + u.x), cur.y + cv * (a1 + u.y));
    }
  }
}

// ---------------- instance norm on first 32 channels, in place ----------------
__global__ __launch_bounds__(256) void inorm_kernel(float* __restrict__ buf,
                                                    const float* __restrict__ nw,
                                                    const float* __restrict__ nb) {
  int c = blockIdx.x;  // 0..31
  int b = blockIdx.y;
  float* p = buf + (((size_t)b * 64 + c) << 14);
  float s = 0.f, s2 = 0.f;
  for (int i = threadIdx.x; i < 4096; i += 256) {
    float4 v = ((const float4*)p)[i];
    s += v.x + v.y + v.z + v.w;
    s2 += v.x * v.x + v.y * v.y + v.z * v.z + v.w * v.w;
  }
  s = wredsum(s); s2 = wredsum(s2);
  __shared__ float rs[4], rs2[4];
  __shared__ float sck, shh;
  int wid = threadIdx.x >> 6;
  if ((threadIdx.x & 63) == 0) { rs[wid] = s; rs2[wid] = s2; }
  __syncthreads();
  if (threadIdx.x == 0) {
    float S = rs[0] + rs[1] + rs[2] + rs[3];
    float S2 = rs2[0] + rs2[1] + rs2[2] + rs2[3];
    float m = S * (1.f / 16384.f);
    float var = S2 * (1.f / 16384.f) - m * m;
    float k = nw[c] * rsqrtf(var + 1e-5f);
    sck = k; shh = nb[c] - m * k;
  }
  __syncthreads();
  float k = sck, h = shh;
  for (int i = threadIdx.x; i < 4096; i += 256) {
    float4 v = ((const float4*)p)[i];
    v.x = v.x * k + h; v.y = v.y * k + h; v.z = v.z * k + h; v.w = v.w * k + h;
    ((float4*)p)[i] = v;
  }
}

// ---------------- g[b,c] = max + mean over HW ----------------
__global__ __launch_bounds__(256) void pool_kernel(const float* __restrict__ xf,
                                                   float* __restrict__ g) {
  int c = blockIdx.x;  // 0..63
  int b = blockIdx.y;
  const float* p = xf + (((size_t)b * 64 + c) << 14);
  float s = 0.f, mx = -3.4e38f;
  for (int i = threadIdx.x; i < 4096; i += 256) {
    float4 v = ((const float4*)p)[i];
    s += v.x + v.y + v.z + v.w;
    mx = fmaxf(mx, fmaxf(fmaxf(v.x, v.y), fmaxf(v.z, v.w)));
  }
  s = wredsum(s); mx = wredmax(mx);
  __shared__ float rs[4], rm[4];
  int wid = threadIdx.x >> 6;
  if ((threadIdx.x & 63) == 0) { rs[wid] = s; rm[wid] = mx; }
  __syncthreads();
  if (threadIdx.x == 0) {
    float S = rs[0] + rs[1] + rs[2] + rs[3];
    float M = fmaxf(fmaxf(rm[0], rm[1]), fmaxf(rm[2], rm[3]));
    g[b * 64 + c] = M + S * (1.f / 16384.f);
  }
}

// ---------------- gating: lg, noise, top-2, softmax -> cof (8x4) ----------------
__global__ void gate_kernel(const float* __restrict__ g, const float* __restrict__ gw0,
                            const float* __restrict__ gb0, const float* __restrict__ gw1,
                            const float* __restrict__ gb1, float* __restrict__ cof) {
  int b = threadIdx.x;
  if (b >= 8) return;
  float lg[4], noise[4];
  for (int e = 0; e < 4; ++e) {
    float a0 = gb0[e], a1 = gb1[e];
    for (int c = 0; c < 64; ++c) {
      float gv = g[b * 64 + c];
      a0 += gv * gw0[e * 64 + c];
      a1 += gv * gw1[e * 64 + c];
    }
    lg[e] = a1 > 0.f ? a1 : 0.2f * a1;
    noise[e] = fmaxf(a0, 0.f) + log1pf(expf(-fabsf(a0)));  // stable softplus
  }
  float nm = 0.25f * (noise[0] + noise[1] + noise[2] + noise[3]);
  float vs = 0.f;
  for (int e = 0; e < 4; ++e) { float d = noise[e] - nm; vs += d * d; }
  float ns = sqrtf(vs / 3.f);  // ddof=1
  float sc[4];
  for (int e = 0; e < 4; ++e) sc[e] = lg[e] + (noise[e] - nm) / ns;
  int i1 = 0;
  for (int e = 1; e < 4; ++e) if (sc[e] > sc[i1]) i1 = e;
  int i2 = -1;
  for (int e = 0; e < 4; ++e) if (e != i1 && (i2 < 0 || sc[e] > sc[i2])) i2 = e;
  float mx = fmaxf(lg[i1], lg[i2]);
  float e1 = expf(lg[i1] - mx), e2 = expf(lg[i2] - mx);
  float d = e1 + e2;
  for (int e = 0; e < 4; ++e) cof[b * 4 + e] = 0.f;
  cof[b * 4 + i1] = e1 / d;
  cof[b * 4 + i2] = e2 / d;
}

extern "C" void kernel_launch(void* const* d_in, const int* in_sizes, int n_in,
                              void* d_out, int out_size, void* d_ws, size_t ws_size,
                              hipStream_t stream) {
  const float* x    = (const float*)d_in[0];
  const float* winv = (const float*)d_in[1];
  const float* w1   = (const float*)d_in[2];
  const float* b1   = (const float*)d_in[3];
  const float* nw   = (const float*)d_in[4];
  const float* nb   = (const float*)d_in[5];
  const float* w2   = (const float*)d_in[6];
  const float* b2   = (const float*)d_in[7];
  const float* fw   = (const float*)d_in[8];
  const float* fb   = (const float*)d_in[9];
  const float* gw0  = (const float*)d_in[10];
  const float* gb0  = (const float*)d_in[11];
  const float* gw1  = (const float*)d_in[12];
  const float* gb1  = (const float*)d_in[13];
  const float* ew1  = (const float*)d_in[14];
  const float* eb1  = (const float*)d_in[15];
  const float* ew2  = (const float*)d_in[16];
  const float* eb2  = (const float*)d_in[17];

  const size_t P = (size_t)8 * 64 * HW2;  // one (8,64,128,128) tensor, in floats
  float* out = (float*)d_out;
  float* cof = out + P;
  float* ws = (float*)d_ws;
  float* zbuf = ws;            // 2P: z = [x1 | x2] interleaved per batch (stride 128 ch)
  float* bufA = ws + 2 * P;    // hin conv1 output; later xf
  float* y1b  = ws + 3 * P;
  float* y2b  = ws + 4 * P;    // later H (expert hidden)
  float* xfb  = bufA;
  float* Eb   = zbuf;          // exp(s) written over x1 planes (stride 128)
  float* Hb   = y2b;
  float* gb   = y1b;           // 512 floats, reuse y1 after fuse

  const float* x1 = zbuf;                          // stride 128
  const float* x2 = zbuf + ((size_t)64 << 14);     // stride 128

  zero_kernel<<<2048, 256, 0, stream>>>(out, out_size);
  mm128_kernel<<<dim3(128, 8), 256, 0, stream>>>(x, winv, zbuf);

  dim3 cg(64, 8);
  // hin0(x2): y1 = x1 + x2 + conv2(inorm-half(conv1(x2)))
  conv3x3_kernel<M_PLAIN><<<cg, 256, 0, stream>>>(x2, 128, w1, b1, bufA, 64,
      nullptr, 0, nullptr, 0, nullptr, 0, nullptr, 0);
  inorm_kernel<<<dim3(32, 8), 256, 0, stream>>>(bufA, nw, nb);
  conv3x3_kernel<M_ADD2><<<cg, 256, 0, stream>>>(bufA, 64, w2, b2, y1b, 64,
      x2, 128, x1, 128, nullptr, 0, nullptr, 0);
  // hin2(y1): E = exp(0.8*(2*sigmoid(y1 + conv2(...)) - 1))  (into x1 planes)
  conv3x3_kernel<M_PLAIN><<<cg, 256, 0, stream>>>(y1b, 64, w1 + 2 * 36864, b1 + 128, bufA, 64,
      nullptr, 0, nullptr, 0, nullptr, 0, nullptr, 0);
  inorm_kernel<<<dim3(32, 8), 256, 0, stream>>>(bufA, nw + 64, nb + 64);
  conv3x3_kernel<M_SIGEXP><<<cg, 256, 0, stream>>>(bufA, 64, w2 + 2 * 36864, b2 + 128, Eb, 128,
      y1b, 64, nullptr, 0, nullptr, 0, nullptr, 0);
  // hin1(y1): y2 = x2*E + y1 + conv2(...)
  conv3x3_kernel<M_PLAIN><<<cg, 256, 0, stream>>>(y1b, 64, w1 + 36864, b1 + 64, bufA, 64,
      nullptr, 0, nullptr, 0, nullptr, 0, nullptr, 0);
  inorm_kernel<<<dim3(32, 8), 256, 0, stream>>>(bufA, nw + 32, nb + 32);
  conv3x3_kernel<M_COUPLE><<<cg, 256, 0, stream>>>(bufA, 64, w2 + 36864, b2 + 64, y2b, 64,
      y1b, 64, x2, 128, Eb, 128, nullptr, 0);
  // xf = 1x1([y1;y2]) + fb
  fuse_kernel<<<cg, 256, 0, stream>>>(y1b, y2b, fw, fb, xfb);
  // gating
  pool_kernel<<<cg, 256, 0, stream>>>(xfb, gb);
  gate_kernel<<<1, 64, 0, stream>>>(gb, gw0, gb0, gw1, gb1, cof);
  // experts: out += cof[b,e] * (conv2(lrelu(conv1(xf))) + b2 + xf); blocks skip cof==0
  for (int e = 0; e < 4; ++e) {
    conv3x3_kernel<M_LRELU><<<cg, 256, 0, stream>>>(xfb, 64, ew1 + (size_t)e * 36864,
        eb1 + e * 64, Hb, 64, nullptr, 0, nullptr, 0, nullptr, 0, cof, e);
    conv3x3_kernel<M_EACC><<<cg, 256, 0, stream>>>(Hb, 64, ew2 + (size_t)e * 36864,
        eb2 + e * 64, out, 64, xfb, 64, nullptr, 0, nullptr, 0, cof, e);
  }
}

// Round 3
// 713.691 us; speedup vs baseline: 3.8286x; 3.8286x over previous
//
#include <hip/hip_runtime.h>
#include <cstddef>

// LfExpert: bf16 MFMA implicit-GEMM version. NHWC bf16 activations, fp32 accum.
// B=8, C=64, E=4, K=2, HW=128.

#define HW2 16384
typedef short short8 __attribute__((ext_vector_type(8)));
typedef float f32x4 __attribute__((ext_vector_type(4)));
typedef unsigned short ushort_t;
typedef unsigned int uint_t;

enum { M_PLAIN = 0, M_ADD2 = 1, M_SIGEXP = 2, M_COUPLE = 3, M_LRELU = 4, M_EACC = 5 };

__device__ __forceinline__ float bf2f(ushort_t u) {
  return __uint_as_float(((uint_t)u) << 16);
}
__device__ __forceinline__ ushort_t f2bf(float f) {
  uint_t u = __float_as_uint(f);
  u += 0x7fffu + ((u >> 16) & 1u);  // RNE
  return (ushort_t)(u >> 16);
}
__device__ __forceinline__ uint_t pack2(float a, float b) {
  return (uint_t)f2bf(a) | ((uint_t)f2bf(b) << 16);
}
__device__ __forceinline__ void ld4bf(const ushort_t* p, float* o) {
  uint2 d = *(const uint2*)p;
  o[0] = bf2f((ushort_t)(d.x & 0xffff)); o[1] = bf2f((ushort_t)(d.x >> 16));
  o[2] = bf2f((ushort_t)(d.y & 0xffff)); o[3] = bf2f((ushort_t)(d.y >> 16));
}
__device__ __forceinline__ void st4bf(ushort_t* p, const float* v) {
  uint2 st; st.x = pack2(v[0], v[1]); st.y = pack2(v[2], v[3]);
  *(uint2*)p = st;
}

// ---------- weight transform: 14 x [co][ci][3][3] f32 -> [conv][tap][co][ci] bf16 ----------
__global__ void wtrans_kernel(const float* __restrict__ bw1, const float* __restrict__ bw2,
                              const float* __restrict__ ew1, const float* __restrict__ ew2,
                              ushort_t* __restrict__ wbuf) {
  int idx = blockIdx.x * 256 + threadIdx.x;  // < 516096
  int ci = idx & 63; int co = (idx >> 6) & 63;
  int rest = idx >> 12;            // conv*9 + tap, < 126
  int tap = rest % 9; int conv = rest / 9;
  const float* src;
  if (conv < 3)       src = bw1 + (size_t)conv * 36864;
  else if (conv < 6)  src = bw2 + (size_t)(conv - 3) * 36864;
  else if (conv < 10) src = ew1 + (size_t)(conv - 6) * 36864;
  else                src = ew2 + (size_t)(conv - 10) * 36864;
  wbuf[idx] = f2bf(src[(co * 64 + ci) * 9 + tap]);
}

__global__ void cvt_kernel(const float* __restrict__ s, ushort_t* __restrict__ d, int n) {
  int i = blockIdx.x * 256 + threadIdx.x;
  if (i < n) d[i] = f2bf(s[i]);
}

// ---------- x NCHW f32 -> NHWC bf16 (C=128) ----------
__global__ __launch_bounds__(256) void xtrans_kernel(const float* __restrict__ x,
                                                     ushort_t* __restrict__ xh) {
  int b = blockIdx.y;
  int oct = blockIdx.x >> 6;                    // 0..15
  int p = ((blockIdx.x & 63) << 8) + threadIdx.x;  // 0..16383
  short8 v;
#pragma unroll
  for (int j = 0; j < 8; ++j)
    v[j] = (short)f2bf(x[((size_t)(b * 128 + oct * 8 + j)) * HW2 + p]);
  *(short8*)(xh + ((size_t)b * HW2 + p) * 128 + oct * 8) = v;
}

// ---------- 3x3 conv 64->64 via MFMA, fused epilogues ----------
// A = weights (rows=co), B = input (cols=pixel). D: row=(lane>>4)*4+r (co), col=lane&15 (px).
template <int MODE, bool INORM>
__global__ __launch_bounds__(256) void conv3_kernel(
    const ushort_t* __restrict__ in, int icstr, int icoff,
    const ushort_t* __restrict__ wgt, const float* __restrict__ bias,
    void* __restrict__ outv, int ocstr, int ocoff,
    const ushort_t* __restrict__ r1, int r1cstr, int r1off,
    const ushort_t* __restrict__ r2, int r2cstr, int r2off,
    const ushort_t* __restrict__ mul, int mcstr, int moff,
    const float* __restrict__ kh, const float* __restrict__ cof, int expert) {
  int b = blockIdx.y;
  float cv = 0.f; bool first = false;
  if (MODE == M_LRELU || MODE == M_EACC) {
    cv = cof[b * 4 + expert];
    if (cv == 0.f) return;  // block-uniform skip
    if (MODE == M_EACC) {
      first = true;
      for (int e2 = 0; e2 < expert; ++e2) if (cof[b * 4 + e2] != 0.f) first = false;
    }
  }
  int tile = blockIdx.x;
  int ty0 = (tile >> 3) << 3;   // 16 y-tiles x 8 rows
  int tx0 = (tile & 7) << 4;    // 8 x-tiles x 16 cols
  int t = threadIdx.x;

  __shared__ __align__(16) ushort_t sm[10 * 18 * 64];  // 23040 B, [row][x][oct^x&7][8]
  char* smb = (char*)sm;

  for (int i = t; i < 1440; i += 256) {
    int oct = i & 7; int xr = i >> 3;
    int xx = xr % 18; int row = xr / 18;
    int gy = ty0 + row - 1, gx = tx0 + xx - 1;
    short8 v = {0, 0, 0, 0, 0, 0, 0, 0};
    if ((unsigned)gy < 128u && (unsigned)gx < 128u)
      v = *(const short8*)(in + ((size_t)b * HW2 + (gy << 7) + gx) * icstr + icoff + oct * 8);
    if (INORM && oct < 4) {  // instance-norm applied to c<32 during staging
      const float* khp = kh + (b * 32 + oct * 8) * 2;
#pragma unroll
      for (int j = 0; j < 8; ++j) {
        float f = bf2f((ushort_t)v[j]);
        v[j] = (short)f2bf(f * khp[j * 2] + khp[j * 2 + 1]);
      }
    }
    *(short8*)(smb + (((row * 18 + xx) * 8 + (oct ^ (xx & 7))) << 4)) = v;
  }
  __syncthreads();

  int lane = t & 63, w = t >> 6;
  int col = lane & 15, krow = lane >> 4;
  f32x4 acc[2][4] = {};

  for (int tap = 0; tap < 9; ++tap) {
    int dy = tap / 3, dx = tap - dy * 3;
#pragma unroll
    for (int h = 0; h < 2; ++h) {
      short8 af[4];
#pragma unroll
      for (int n = 0; n < 4; ++n)
        af[n] = *(const short8*)(wgt + (tap * 64 + n * 16 + col) * 64 + h * 32 + krow * 8);
      short8 bfr[2];
#pragma unroll
      for (int s = 0; s < 2; ++s) {
        int row = 2 * w + s + dy, xx = col + dx;
        bfr[s] = *(const short8*)(smb +
                 (((row * 18 + xx) * 8 + ((h * 4 + krow) ^ (xx & 7))) << 4));
      }
#pragma unroll
      for (int s = 0; s < 2; ++s)
#pragma unroll
        for (int n = 0; n < 4; ++n)
          acc[s][n] = __builtin_amdgcn_mfma_f32_16x16x32_bf16(af[n], bfr[s], acc[s][n], 0, 0, 0);
    }
  }

#pragma unroll
  for (int s = 0; s < 2; ++s) {
    int py = ty0 + 2 * w + s;
    size_t pix = (size_t)b * HW2 + (py << 7) + tx0 + col;
#pragma unroll
    for (int n = 0; n < 4; ++n) {
      int cb = n * 16 + krow * 4;
      float v[4];
#pragma unroll
      for (int r = 0; r < 4; ++r) v[r] = acc[s][n][r] + bias[cb + r];
      if (MODE == M_PLAIN) {
        st4bf((ushort_t*)outv + pix * ocstr + ocoff + cb, v);
      } else if (MODE == M_ADD2) {
        float a[4], bb[4];
        ld4bf(r1 + pix * r1cstr + r1off + cb, a);
        ld4bf(r2 + pix * r2cstr + r2off + cb, bb);
#pragma unroll
        for (int r = 0; r < 4; ++r) v[r] += a[r] + bb[r];
        st4bf((ushort_t*)outv + pix * ocstr + ocoff + cb, v);
      } else if (MODE == M_SIGEXP) {
        float a[4];
        ld4bf(r1 + pix * r1cstr + r1off + cb, a);
#pragma unroll
        for (int r = 0; r < 4; ++r) {
          float tt = v[r] + a[r];
          float sg = 1.f / (1.f + __expf(-tt));
          v[r] = __expf(1.6f * sg - 0.8f);
        }
        st4bf((ushort_t*)outv + pix * ocstr + ocoff + cb, v);
      } else if (MODE == M_COUPLE) {
        float a[4], bb[4], mm[4];
        ld4bf(r1 + pix * r1cstr + r1off + cb, a);
        ld4bf(r2 + pix * r2cstr + r2off + cb, bb);
        ld4bf(mul + pix * mcstr + moff + cb, mm);
#pragma unroll
        for (int r = 0; r < 4; ++r) v[r] += a[r] + bb[r] * mm[r];
        st4bf((ushort_t*)outv + pix * ocstr + ocoff + cb, v);
      } else if (MODE == M_LRELU) {
#pragma unroll
        for (int r = 0; r < 4; ++r) v[r] = v[r] > 0.f ? v[r] : 0.2f * v[r];
        st4bf((ushort_t*)outv + pix * ocstr + ocoff + cb, v);
      } else if (MODE == M_EACC) {
        float a[4];
        ld4bf(r1 + pix * r1cstr + r1off + cb, a);  // xf
        f32x4 val;
#pragma unroll
        for (int r = 0; r < 4; ++r) val[r] = cv * (v[r] + a[r]);
        float* ap = (float*)outv + pix * 64 + cb;
        if (first) *(f32x4*)ap = val;
        else { f32x4 old = *(f32x4*)ap; *(f32x4*)ap = old + val; }
      }
    }
  }
}

// ---------- 1x1 conv (K=128) via MFMA, no LDS ----------
template <int NF>  // NF = NCO/16
__global__ __launch_bounds__(256) void mm1_kernel(
    const ushort_t* __restrict__ in, int icstr,
    const ushort_t* __restrict__ wgt, const float* __restrict__ bias,
    ushort_t* __restrict__ out, int ocstr) {
  int b = blockIdx.y;
  int p0 = blockIdx.x << 7;
  int t = threadIdx.x, lane = t & 63, w = t >> 6;
  int col = lane & 15, krow = lane >> 4;
  f32x4 acc[2][NF] = {};
  size_t pixb = (size_t)b * HW2 + p0 + w * 32;
#pragma unroll
  for (int kk = 0; kk < 4; ++kk) {
    short8 bfr[2];
#pragma unroll
    for (int s = 0; s < 2; ++s)
      bfr[s] = *(const short8*)(in + (pixb + s * 16 + col) * icstr + kk * 32 + krow * 8);
#pragma unroll
    for (int n = 0; n < NF; ++n) {
      short8 af = *(const short8*)(wgt + (n * 16 + col) * 128 + kk * 32 + krow * 8);
#pragma unroll
      for (int s = 0; s < 2; ++s)
        acc[s][n] = __builtin_amdgcn_mfma_f32_16x16x32_bf16(af, bfr[s], acc[s][n], 0, 0, 0);
    }
  }
#pragma unroll
  for (int s = 0; s < 2; ++s) {
    size_t pix = pixb + s * 16 + col;
#pragma unroll
    for (int n = 0; n < NF; ++n) {
      int cb = n * 16 + krow * 4;
      float v[4];
#pragma unroll
      for (int r = 0; r < 4; ++r) v[r] = acc[s][n][r] + (bias ? bias[cb + r] : 0.f);
      st4bf(out + pix * ocstr + cb, v);
    }
  }
}

// ---------- instance-norm partial reduce over h (c<32) ----------
__global__ __launch_bounds__(256) void ireduce_kernel(const ushort_t* __restrict__ h,
                                                      float* __restrict__ part) {
  int b = blockIdx.y, chunk = blockIdx.x, t = threadIdx.x;
  int c = t & 31, g = t >> 5;
  float s = 0.f, q = 0.f;
  const ushort_t* base = h + ((size_t)b * HW2 + chunk * 512) * 64 + c;
  for (int i = 0; i < 64; ++i) {
    float f = bf2f(base[(g + i * 8) * 64]);
    s += f; q += f * f;
  }
  __shared__ float ls[8][32], lq[8][32];
  ls[g][c] = s; lq[g][c] = q;
  __syncthreads();
  if (t < 32) {
    float S = 0.f, Q = 0.f;
    for (int gg = 0; gg < 8; ++gg) { S += ls[gg][t]; Q += lq[gg][t]; }
    float* pp = part + ((b * 32 + chunk) * 32 + t) * 2;
    pp[0] = S; pp[1] = Q;
  }
}

__global__ void istat_kernel(const float* __restrict__ part, const float* __restrict__ nw,
                             const float* __restrict__ nb, float* __restrict__ kh) {
  int t = threadIdx.x; if (t >= 256) return;
  int b = t >> 5, c = t & 31;
  float S = 0.f, Q = 0.f;
  for (int ch = 0; ch < 32; ++ch) {
    const float* pp = part + ((b * 32 + ch) * 32 + c) * 2;
    S += pp[0]; Q += pp[1];
  }
  float m = S * (1.f / 16384.f);
  float var = Q * (1.f / 16384.f) - m * m;
  float k = nw[c] * rsqrtf(var + 1e-5f);
  kh[(b * 32 + c) * 2] = k;
  kh[(b * 32 + c) * 2 + 1] = nb[c] - m * k;
}

// ---------- pooling partials (sum, max) over xf ----------
__global__ __launch_bounds__(256) void preduce_kernel(const ushort_t* __restrict__ xf,
                                                      float* __restrict__ part2) {
  int b = blockIdx.y, chunk = blockIdx.x, t = threadIdx.x;
  int c = t & 63, g = t >> 6;
  float s = 0.f, mx = -3.4e38f;
  const ushort_t* base = xf + ((size_t)b * HW2 + chunk * 512) * 64 + c;
  for (int i = 0; i < 128; ++i) {
    float f = bf2f(base[(g + i * 4) * 64]);
    s += f; mx = fmaxf(mx, f);
  }
  __shared__ float ls[4][64], lm[4][64];
  ls[g][c] = s; lm[g][c] = mx;
  __syncthreads();
  if (t < 64) {
    float S = ls[0][t] + ls[1][t] + ls[2][t] + ls[3][t];
    float M = fmaxf(fmaxf(lm[0][t], lm[1][t]), fmaxf(lm[2][t], lm[3][t]));
    float* pp = part2 + ((b * 32 + chunk) * 64 + t) * 2;
    pp[0] = S; pp[1] = M;
  }
}

__global__ void pool2_kernel(const float* __restrict__ part2, float* __restrict__ g) {
  int t = blockIdx.x * blockDim.x + threadIdx.x;
  if (t >= 512) return;
  int b = t >> 6, c = t & 63;
  float S = 0.f, M = -3.4e38f;
  for (int ch = 0; ch < 32; ++ch) {
    const float* pp = part2 + ((b * 32 + ch) * 64 + c) * 2;
    S += pp[0]; M = fmaxf(M, pp[1]);
  }
  g[t] = M + S * (1.f / 16384.f);
}

// ---------- gating ----------
__global__ void gate_kernel(const float* __restrict__ g, const float* __restrict__ gw0,
                            const float* __restrict__ gb0, const float* __restrict__ gw1,
                            const float* __restrict__ gb1, float* __restrict__ cof) {
  int b = threadIdx.x;
  if (b >= 8) return;
  float lg[4], noise[4];
  for (int e = 0; e < 4; ++e) {
    float a0 = gb0[e], a1 = gb1[e];
    for (int c = 0; c < 64; ++c) {
      float gv = g[b * 64 + c];
      a0 += gv * gw0[e * 64 + c];
      a1 += gv * gw1[e * 64 + c];
    }
    lg[e] = a1 > 0.f ? a1 : 0.2f * a1;
    noise[e] = fmaxf(a0, 0.f) + log1pf(expf(-fabsf(a0)));
  }
  float nm = 0.25f * (noise[0] + noise[1] + noise[2] + noise[3]);
  float vs = 0.f;
  for (int e = 0; e < 4; ++e) { float d = noise[e] - nm; vs += d * d; }
  float ns = sqrtf(vs / 3.f);
  float sc[4];
  for (int e = 0; e < 4; ++e) sc[e] = lg[e] + (noise[e] - nm) / ns;
  int i1 = 0;
  for (int e = 1; e < 4; ++e) if (sc[e] > sc[i1]) i1 = e;
  int i2 = -1;
  for (int e = 0; e < 4; ++e) if (e != i1 && (i2 < 0 || sc[e] > sc[i2])) i2 = e;
  float mx = fmaxf(lg[i1], lg[i2]);
  float e1 = expf(lg[i1] - mx), e2 = expf(lg[i2] - mx);
  float d = e1 + e2;
  for (int e = 0; e < 4; ++e) cof[b * 4 + e] = 0.f;
  cof[b * 4 + i1] = e1 / d;
  cof[b * 4 + i2] = e2 / d;
}

// ---------- NHWC f32 acc -> NCHW f32 out ----------
__global__ __launch_bounds__(256) void nchw_kernel(const float* __restrict__ acc,
                                                   float* __restrict__ out) {
  int b = blockIdx.y, pix0 = blockIdx.x << 6, t = threadIdx.x;
  __shared__ float ts[64][68];
  for (int i = t; i < 1024; i += 256) {
    int px = i >> 4, grp = i & 15;
    f32x4 v = *(const f32x4*)(acc + ((size_t)b * HW2 + pix0 + px) * 64 + grp * 4);
    *(f32x4*)(&ts[px][grp * 4]) = v;
  }
  __syncthreads();
  int c = t >> 2, xg = t & 3;
#pragma unroll
  for (int j = 0; j < 4; ++j) {
    int px = xg * 16 + j * 4;
    f32x4 o;
#pragma unroll
    for (int k = 0; k < 4; ++k) o[k] = ts[px + k][c];
    *(f32x4*)(out + (((size_t)b * 64 + c) << 14) + pix0 + px) = o;
  }
}

extern "C" void kernel_launch(void* const* d_in, const int* in_sizes, int n_in,
                              void* d_out, int out_size, void* d_ws, size_t ws_size,
                              hipStream_t stream) {
  const float* x    = (const float*)d_in[0];
  const float* winv = (const float*)d_in[1];
  const float* w1   = (const float*)d_in[2];
  const float* b1   = (const float*)d_in[3];
  const float* nw   = (const float*)d_in[4];
  const float* nb   = (const float*)d_in[5];
  const float* w2   = (const float*)d_in[6];
  const float* b2   = (const float*)d_in[7];
  const float* fw   = (const float*)d_in[8];
  const float* fb   = (const float*)d_in[9];
  const float* gw0  = (const float*)d_in[10];
  const float* gb0  = (const float*)d_in[11];
  const float* gw1  = (const float*)d_in[12];
  const float* gb1  = (const float*)d_in[13];
  const float* ew1  = (const float*)d_in[14];
  const float* eb1  = (const float*)d_in[15];
  const float* ew2  = (const float*)d_in[16];
  const float* eb2  = (const float*)d_in[17];

  char* W = (char*)d_ws;
  ushort_t* A    = (ushort_t*)(W);               // 33.5MB: xhwc, then ycat [y1|y2]
  ushort_t* Bz   = (ushort_t*)(W + 33554432);    // 33.5MB: z [x1|x2]; later acc f32
  float*    accb = (float*)(W + 33554432);
  ushort_t* Ch   = (ushort_t*)(W + 67108864);    // 16.8MB: h / expert hidden
  ushort_t* Dx   = (ushort_t*)(W + 83886080);    // 16.8MB: E / xf
  ushort_t* w3   = (ushort_t*)(W + 100663296);   // [14][9][64][64] bf16
  ushort_t* wmm  = (ushort_t*)(W + 101695488);   // winv bf16 [128][128]
  ushort_t* wfu  = (ushort_t*)(W + 101728256);   // fuse bf16 [64][128]
  float* part1 = (float*)(W + 101744640);
  float* kh    = (float*)(W + 101810176);
  float* part2 = (float*)(W + 101812224);
  float* gbuf  = (float*)(W + 101943296);

  float* out = (float*)d_out;
  float* cof = out + (size_t)8 * 64 * HW2;

  const int WS3 = 36864;  // per-conv weight stride (ushorts)
  dim3 cg(128, 8), rg(32, 8);

  wtrans_kernel<<<2016, 256, 0, stream>>>(w1, w2, ew1, ew2, w3);
  cvt_kernel<<<64, 256, 0, stream>>>(winv, wmm, 16384);
  cvt_kernel<<<32, 256, 0, stream>>>(fw, wfu, 8192);
  xtrans_kernel<<<dim3(1024, 8), 256, 0, stream>>>(x, A);

  // z = winv @ x  (C=128 NHWC): x1=ch0-63, x2=ch64-127
  mm1_kernel<8><<<cg, 256, 0, stream>>>(A, 128, wmm, nullptr, Bz, 128);

  // hin0(x2): y1 = x1 + x2 + conv2(inorm_half(conv1(x2)))
  conv3_kernel<M_PLAIN, false><<<cg, 256, 0, stream>>>(Bz, 128, 64, w3 + 0 * WS3, b1,
      Ch, 64, 0, nullptr,0,0, nullptr,0,0, nullptr,0,0, kh, nullptr, 0);
  ireduce_kernel<<<rg, 256, 0, stream>>>(Ch, part1);
  istat_kernel<<<1, 256, 0, stream>>>(part1, nw, nb, kh);
  conv3_kernel<M_ADD2, true><<<cg, 256, 0, stream>>>(Ch, 64, 0, w3 + 3 * WS3, b2,
      A, 128, 0, Bz, 128, 64, Bz, 128, 0, nullptr,0,0, kh, nullptr, 0);

  // hin2(y1): E = exp(0.8*(2*sigmoid(y1 + conv2(inorm_half(conv1(y1)))) - 1))
  conv3_kernel<M_PLAIN, false><<<cg, 256, 0, stream>>>(A, 128, 0, w3 + 2 * WS3, b1 + 128,
      Ch, 64, 0, nullptr,0,0, nullptr,0,0, nullptr,0,0, kh, nullptr, 0);
  ireduce_kernel<<<rg, 256, 0, stream>>>(Ch, part1);
  istat_kernel<<<1, 256, 0, stream>>>(part1, nw + 64, nb + 64, kh);
  conv3_kernel<M_SIGEXP, true><<<cg, 256, 0, stream>>>(Ch, 64, 0, w3 + 5 * WS3, b2 + 128,
      Dx, 64, 0, A, 128, 0, nullptr,0,0, nullptr,0,0, kh, nullptr, 0);

  // hin1(y1): y2 = x2*E + y1 + conv2(inorm_half(conv1(y1)))
  conv3_kernel<M_PLAIN, false><<<cg, 256, 0, stream>>>(A, 128, 0, w3 + 1 * WS3, b1 + 64,
      Ch, 64, 0, nullptr,0,0, nullptr,0,0, nullptr,0,0, kh, nullptr, 0);
  ireduce_kernel<<<rg, 256, 0, stream>>>(Ch, part1);
  istat_kernel<<<1, 256, 0, stream>>>(part1, nw + 32, nb + 32, kh);
  conv3_kernel<M_COUPLE, true><<<cg, 256, 0, stream>>>(Ch, 64, 0, w3 + 4 * WS3, b2 + 64,
      A, 128, 64, A, 128, 0, Bz, 128, 64, Dx, 64, 0, kh, nullptr, 0);

  // xf = fuse_w @ [y1;y2] + fb   (into Dx; E is dead)
  mm1_kernel<4><<<cg, 256, 0, stream>>>(A, 128, wfu, fb, Dx, 64);

  // gating
  preduce_kernel<<<rg, 256, 0, stream>>>(Dx, part2);
  pool2_kernel<<<2, 256, 0, stream>>>(part2, gbuf);
  gate_kernel<<<1, 64, 0, stream>>>(gbuf, gw0, gb0, gw1, gb1, cof);

  // experts: acc(NHWC f32) = sum_e cof_e * (conv2(lrelu(conv1(xf))) + xf)
  for (int e = 0; e < 4; ++e) {
    conv3_kernel<M_LRELU, false><<<cg, 256, 0, stream>>>(Dx, 64, 0, w3 + (6 + e) * WS3,
        eb1 + e * 64, Ch, 64, 0, nullptr,0,0, nullptr,0,0, nullptr,0,0, kh, cof, e);
    conv3_kernel<M_EACC, false><<<cg, 256, 0, stream>>>(Ch, 64, 0, w3 + (10 + e) * WS3,
        eb2 + e * 64, (void*)accb, 64, 0, Dx, 64, 0, nullptr,0,0, nullptr,0,0, kh, cof, e);
  }

  nchw_kernel<<<dim3(256, 8), 256, 0, stream>>>(accb, out);
}

// Round 5
// 503.018 us; speedup vs baseline: 5.4321x; 1.4188x over previous
//
#include <hip/hip_runtime.h>
#include <cstddef>

// LfExpert: bf16 MFMA implicit-GEMM. NHWC bf16 activations, fp32 accum.
// R5: fix R4's weight-chunk stride bug (<<10 -> <<9: chunks are 512 ushorts
// = 1KB). Everything else identical to R4 (async global_load_lds staging,
// 16x16 tile, acc[4][4]/wave, INORM halo fix).

#define HW2 16384
typedef short short8 __attribute__((ext_vector_type(8)));
typedef float f32x4 __attribute__((ext_vector_type(4)));
typedef unsigned short ushort_t;
typedef unsigned int uint_t;

enum { M_PLAIN = 0, M_ADD2 = 1, M_SIGEXP = 2, M_COUPLE = 3, M_LRELU = 4, M_EACC = 5 };

__device__ __forceinline__ float bf2f(ushort_t u) {
  return __uint_as_float(((uint_t)u) << 16);
}
__device__ __forceinline__ ushort_t f2bf(float f) {
  uint_t u = __float_as_uint(f);
  u += 0x7fffu + ((u >> 16) & 1u);  // RNE
  return (ushort_t)(u >> 16);
}
__device__ __forceinline__ uint_t pack2(float a, float b) {
  return (uint_t)f2bf(a) | ((uint_t)f2bf(b) << 16);
}
__device__ __forceinline__ void ld4bf(const ushort_t* p, float* o) {
  uint2 d = *(const uint2*)p;
  o[0] = bf2f((ushort_t)(d.x & 0xffff)); o[1] = bf2f((ushort_t)(d.x >> 16));
  o[2] = bf2f((ushort_t)(d.y & 0xffff)); o[3] = bf2f((ushort_t)(d.y >> 16));
}
__device__ __forceinline__ void st4bf(ushort_t* p, const float* v) {
  uint2 st; st.x = pack2(v[0], v[1]); st.y = pack2(v[2], v[3]);
  *(uint2*)p = st;
}
__device__ __forceinline__ void gload_lds16(const void* g, void* l) {
  __builtin_amdgcn_global_load_lds(
      (const __attribute__((address_space(1))) void*)g,
      (__attribute__((address_space(3))) void*)l, 16, 0, 0);
}

// ---------- weight transform: [co][ci][3][3] f32 -> chunked bf16 ----------
// chunk c = (tap*2+h)*4+n, 512 ushorts each; lane offset (col*4+krow)*8+e.
// af addr (ushorts) = conv*36864 + (c<<9) + (col*4+krow)*8
__global__ void wtrans_kernel(const float* __restrict__ bw1, const float* __restrict__ bw2,
                              const float* __restrict__ ew1, const float* __restrict__ ew2,
                              ushort_t* __restrict__ wbuf) {
  int idx = blockIdx.x * 256 + threadIdx.x;  // < 516096
  int ci = idx & 63; int co = (idx >> 6) & 63;
  int rest = idx >> 12;            // conv*9 + tap, < 126
  int tap = rest % 9; int conv = rest / 9;
  const float* src;
  if (conv < 3)       src = bw1 + (size_t)conv * 36864;
  else if (conv < 6)  src = bw2 + (size_t)(conv - 3) * 36864;
  else if (conv < 10) src = ew1 + (size_t)(conv - 6) * 36864;
  else                src = ew2 + (size_t)(conv - 10) * 36864;
  float v = src[(co * 64 + ci) * 9 + tap];
  int n = co >> 4, col = co & 15;
  int h = ci >> 5, krow = (ci >> 3) & 3, e = ci & 7;
  int pos = conv * 36864 + (((tap * 2 + h) * 4 + n) << 9) + ((col << 2) + krow) * 8 + e;
  wbuf[pos] = f2bf(v);
}

__global__ void cvt_kernel(const float* __restrict__ s, ushort_t* __restrict__ d, int n) {
  int i = blockIdx.x * 256 + threadIdx.x;
  if (i < n) d[i] = f2bf(s[i]);
}

// ---------- x NCHW f32 -> NHWC bf16 (C=128) ----------
__global__ __launch_bounds__(256) void xtrans_kernel(const float* __restrict__ x,
                                                     ushort_t* __restrict__ xh) {
  int b = blockIdx.y;
  int oct = blockIdx.x >> 6;                    // 0..15
  int p = ((blockIdx.x & 63) << 8) + threadIdx.x;  // 0..16383
  short8 v;
#pragma unroll
  for (int j = 0; j < 8; ++j)
    v[j] = (short)f2bf(x[((size_t)(b * 128 + oct * 8 + j)) * HW2 + p]);
  *(short8*)(xh + ((size_t)b * HW2 + p) * 128 + oct * 8) = v;
}

// ---------- 3x3 conv 64->64 via MFMA, fused epilogues ----------
// Tile: 16 rows x 16 cols x 64 co per block (4 waves; wave w owns rows 4w..4w+3).
// LDS slots j=(row*18+xx)*8+octS, octS = oct ^ (xx&7); slot holds 8 ci (16B).
template <int MODE, bool INORM>
__global__ __launch_bounds__(256, 2) void conv3_kernel(
    const ushort_t* __restrict__ in, int icstr, int icoff,
    const ushort_t* __restrict__ wgt, const float* __restrict__ bias,
    void* __restrict__ outv, int ocstr, int ocoff,
    const ushort_t* __restrict__ r1, int r1cstr, int r1off,
    const ushort_t* __restrict__ r2, int r2cstr, int r2off,
    const ushort_t* __restrict__ mul, int mcstr, int moff,
    const float* __restrict__ kh, const float* __restrict__ cof, int expert) {
  int b = blockIdx.y;
  float cv = 0.f; bool first = false;
  if (MODE == M_LRELU || MODE == M_EACC) {
    cv = cof[b * 4 + expert];
    if (cv == 0.f) return;  // block-uniform skip
    if (MODE == M_EACC) {
      first = true;
      for (int e2 = 0; e2 < expert; ++e2) if (cof[b * 4 + e2] != 0.f) first = false;
    }
  }
  int tile = blockIdx.x;
  int ty0 = (tile >> 3) << 4;   // 8 y-tiles x 16 rows
  int tx0 = (tile & 7) << 4;    // 8 x-tiles x 16 cols
  int t = threadIdx.x;
  int lane = t & 63, w = t >> 6;

  __shared__ __align__(16) ushort_t sm[2592 * 8];  // 41472 B
  char* smb = (char*)sm;

  if (!INORM) {
    // zero-fill OOB halo slots (disjoint from async-loaded slots)
    for (int j = t; j < 2592; j += 256) {
      int row = j / 144, rem = j - row * 144;
      int xx = rem >> 3;
      int gy = ty0 + row - 1, gx = tx0 + xx - 1;
      if ((unsigned)gy >= 128u || (unsigned)gx >= 128u) {
        short8 z = {0, 0, 0, 0, 0, 0, 0, 0};
        *(short8*)(smb + (j << 4)) = z;
      }
    }
    // async staging: linear LDS dest, per-lane global addr carries the swizzle
    for (int k = w; k < 41; k += 4) {
      int j = (k << 6) + lane;
      int row = j / 144, rem = j - row * 144;
      int xx = rem >> 3, octS = rem & 7;
      int oct = octS ^ (xx & 7);
      int gy = ty0 + row - 1, gx = tx0 + xx - 1;
      if (j < 2592 && (unsigned)gy < 128u && (unsigned)gx < 128u) {
        const ushort_t* gp =
            in + ((size_t)b * HW2 + (gy << 7) + gx) * icstr + icoff + oct * 8;
        gload_lds16(gp, smb + (k << 10));
      }
    }
  } else {
    // register staging (instance-norm applied in flight, padding stays 0)
    short8 v[11];
#pragma unroll
    for (int k = 0; k < 11; ++k) {
      int j = t + (k << 8);
      short8 vv = {0, 0, 0, 0, 0, 0, 0, 0};
      if (j < 2592) {
        int row = j / 144, rem = j - row * 144;
        int xx = rem >> 3, octS = rem & 7;
        int oct = octS ^ (xx & 7);
        int gy = ty0 + row - 1, gx = tx0 + xx - 1;
        if ((unsigned)gy < 128u && (unsigned)gx < 128u) {
          vv = *(const short8*)(in + ((size_t)b * HW2 + (gy << 7) + gx) * icstr + icoff + oct * 8);
          if (oct < 4) {  // c<32 normalized; zero-padding NOT normalized
            const float* khp = kh + (b * 32 + oct * 8) * 2;
#pragma unroll
            for (int jq = 0; jq < 8; ++jq) {
              float f = bf2f((ushort_t)vv[jq]);
              vv[jq] = (short)f2bf(f * khp[jq * 2] + khp[jq * 2 + 1]);
            }
          }
        }
      }
      v[k] = vv;
    }
#pragma unroll
    for (int k = 0; k < 11; ++k) {
      int j = t + (k << 8);
      if (j < 2592) *(short8*)(smb + (j << 4)) = v[k];
    }
  }
  __syncthreads();

  int col = lane & 15, krow = lane >> 4;
  int wofs = ((col << 2) + krow) * 8;  // lane offset within 512-ushort chunk
  f32x4 acc[4][4] = {};

#pragma unroll
  for (int tap = 0; tap < 9; ++tap) {
    const int dy = tap / 3, dx = tap - dy * 3;
#pragma unroll
    for (int h = 0; h < 2; ++h) {
      short8 af[4];
      const ushort_t* wbase = wgt + (((tap * 2 + h) * 4) << 9) + wofs;
#pragma unroll
      for (int n = 0; n < 4; ++n) af[n] = *(const short8*)(wbase + (n << 9));
      short8 bfr[4];
#pragma unroll
      for (int s = 0; s < 4; ++s) {
        int row = (w << 2) + s + dy, xx = col + dx;
        bfr[s] = *(const short8*)(smb +
                 (((row * 18 + xx) * 8 + ((h * 4 + krow) ^ (xx & 7))) << 4));
      }
#pragma unroll
      for (int s = 0; s < 4; ++s)
#pragma unroll
        for (int n = 0; n < 4; ++n)
          acc[s][n] = __builtin_amdgcn_mfma_f32_16x16x32_bf16(af[n], bfr[s], acc[s][n], 0, 0, 0);
    }
  }

#pragma unroll
  for (int s = 0; s < 4; ++s) {
    int py = ty0 + (w << 2) + s;
    size_t pix = (size_t)b * HW2 + (py << 7) + tx0 + col;
#pragma unroll
    for (int n = 0; n < 4; ++n) {
      int cb = n * 16 + krow * 4;
      float v[4];
#pragma unroll
      for (int r = 0; r < 4; ++r) v[r] = acc[s][n][r] + bias[cb + r];
      if (MODE == M_PLAIN) {
        st4bf((ushort_t*)outv + pix * ocstr + ocoff + cb, v);
      } else if (MODE == M_ADD2) {
        float a[4], bb[4];
        ld4bf(r1 + pix * r1cstr + r1off + cb, a);
        ld4bf(r2 + pix * r2cstr + r2off + cb, bb);
#pragma unroll
        for (int r = 0; r < 4; ++r) v[r] += a[r] + bb[r];
        st4bf((ushort_t*)outv + pix * ocstr + ocoff + cb, v);
      } else if (MODE == M_SIGEXP) {
        float a[4];
        ld4bf(r1 + pix * r1cstr + r1off + cb, a);
#pragma unroll
        for (int r = 0; r < 4; ++r) {
          float tt = v[r] + a[r];
          float sg = 1.f / (1.f + __expf(-tt));
          v[r] = __expf(1.6f * sg - 0.8f);
        }
        st4bf((ushort_t*)outv + pix * ocstr + ocoff + cb, v);
      } else if (MODE == M_COUPLE) {
        float a[4], bb[4], mm[4];
        ld4bf(r1 + pix * r1cstr + r1off + cb, a);
        ld4bf(r2 + pix * r2cstr + r2off + cb, bb);
        ld4bf(mul + pix * mcstr + moff + cb, mm);
#pragma unroll
        for (int r = 0; r < 4; ++r) v[r] += a[r] + bb[r] * mm[r];
        st4bf((ushort_t*)outv + pix * ocstr + ocoff + cb, v);
      } else if (MODE == M_LRELU) {
#pragma unroll
        for (int r = 0; r < 4; ++r) v[r] = v[r] > 0.f ? v[r] : 0.2f * v[r];
        st4bf((ushort_t*)outv + pix * ocstr + ocoff + cb, v);
      } else if (MODE == M_EACC) {
        float a[4];
        ld4bf(r1 + pix * r1cstr + r1off + cb, a);  // xf
        f32x4 val;
#pragma unroll
        for (int r = 0; r < 4; ++r) val[r] = cv * (v[r] + a[r]);
        float* ap = (float*)outv + pix * 64 + cb;
        if (first) *(f32x4*)ap = val;
        else { f32x4 old = *(f32x4*)ap; *(f32x4*)ap = old + val; }
      }
    }
  }
}

// ---------- 1x1 conv (K=128) via MFMA, no LDS ----------
template <int NF>  // NF = NCO/16
__global__ __launch_bounds__(256) void mm1_kernel(
    const ushort_t* __restrict__ in, int icstr,
    const ushort_t* __restrict__ wgt, const float* __restrict__ bias,
    ushort_t* __restrict__ out, int ocstr) {
  int b = blockIdx.y;
  int p0 = blockIdx.x << 7;
  int t = threadIdx.x, lane = t & 63, w = t >> 6;
  int col = lane & 15, krow = lane >> 4;
  f32x4 acc[2][NF] = {};
  size_t pixb = (size_t)b * HW2 + p0 + w * 32;
#pragma unroll
  for (int kk = 0; kk < 4; ++kk) {
    short8 bfr[2];
#pragma unroll
    for (int s = 0; s < 2; ++s)
      bfr[s] = *(const short8*)(in + (pixb + s * 16 + col) * icstr + kk * 32 + krow * 8);
#pragma unroll
    for (int n = 0; n < NF; ++n) {
      short8 af = *(const short8*)(wgt + (n * 16 + col) * 128 + kk * 32 + krow * 8);
#pragma unroll
      for (int s = 0; s < 2; ++s)
        acc[s][n] = __builtin_amdgcn_mfma_f32_16x16x32_bf16(af, bfr[s], acc[s][n], 0, 0, 0);
    }
  }
#pragma unroll
  for (int s = 0; s < 2; ++s) {
    size_t pix = pixb + s * 16 + col;
#pragma unroll
    for (int n = 0; n < NF; ++n) {
      int cb = n * 16 + krow * 4;
      float v[4];
#pragma unroll
      for (int r = 0; r < 4; ++r) v[r] = acc[s][n][r] + (bias ? bias[cb + r] : 0.f);
      st4bf(out + pix * ocstr + cb, v);
    }
  }
}

// ---------- instance-norm partial reduce over h (c<32) ----------
__global__ __launch_bounds__(256) void ireduce_kernel(const ushort_t* __restrict__ h,
                                                      float* __restrict__ part) {
  int b = blockIdx.y, chunk = blockIdx.x, t = threadIdx.x;
  int c = t & 31, g = t >> 5;
  float s = 0.f, q = 0.f;
  const ushort_t* base = h + ((size_t)b * HW2 + chunk * 512) * 64 + c;
  for (int i = 0; i < 64; ++i) {
    float f = bf2f(base[(g + i * 8) * 64]);
    s += f; q += f * f;
  }
  __shared__ float ls[8][32], lq[8][32];
  ls[g][c] = s; lq[g][c] = q;
  __syncthreads();
  if (t < 32) {
    float S = 0.f, Q = 0.f;
    for (int gg = 0; gg < 8; ++gg) { S += ls[gg][t]; Q += lq[gg][t]; }
    float* pp = part + ((b * 32 + chunk) * 32 + t) * 2;
    pp[0] = S; pp[1] = Q;
  }
}

__global__ void istat_kernel(const float* __restrict__ part, const float* __restrict__ nw,
                             const float* __restrict__ nb, float* __restrict__ kh) {
  int t = threadIdx.x; if (t >= 256) return;
  int b = t >> 5, c = t & 31;
  float S = 0.f, Q = 0.f;
  for (int ch = 0; ch < 32; ++ch) {
    const float* pp = part + ((b * 32 + ch) * 32 + c) * 2;
    S += pp[0]; Q += pp[1];
  }
  float m = S * (1.f / 16384.f);
  float var = Q * (1.f / 16384.f) - m * m;
  float k = nw[c] * rsqrtf(var + 1e-5f);
  kh[(b * 32 + c) * 2] = k;
  kh[(b * 32 + c) * 2 + 1] = nb[c] - m * k;
}

// ---------- pooling partials (sum, max) over xf ----------
__global__ __launch_bounds__(256) void preduce_kernel(const ushort_t* __restrict__ xf,
                                                      float* __restrict__ part2) {
  int b = blockIdx.y, chunk = blockIdx.x, t = threadIdx.x;
  int c = t & 63, g = t >> 6;
  float s = 0.f, mx = -3.4e38f;
  const ushort_t* base = xf + ((size_t)b * HW2 + chunk * 512) * 64 + c;
  for (int i = 0; i < 128; ++i) {
    float f = bf2f(base[(g + i * 4) * 64]);
    s += f; mx = fmaxf(mx, f);
  }
  __shared__ float ls[4][64], lm[4][64];
  ls[g][c] = s; lm[g][c] = mx;
  __syncthreads();
  if (t < 64) {
    float S = ls[0][t] + ls[1][t] + ls[2][t] + ls[3][t];
    float M = fmaxf(fmaxf(lm[0][t], lm[1][t]), fmaxf(lm[2][t], lm[3][t]));
    float* pp = part2 + ((b * 32 + chunk) * 64 + t) * 2;
    pp[0] = S; pp[1] = M;
  }
}

__global__ void pool2_kernel(const float* __restrict__ part2, float* __restrict__ g) {
  int t = blockIdx.x * blockDim.x + threadIdx.x;
  if (t >= 512) return;
  int b = t >> 6, c = t & 63;
  float S = 0.f, M = -3.4e38f;
  for (int ch = 0; ch < 32; ++ch) {
    const float* pp = part2 + ((b * 32 + ch) * 64 + c) * 2;
    S += pp[0]; M = fmaxf(M, pp[1]);
  }
  g[t] = M + S * (1.f / 16384.f);
}

// ---------- gating ----------
__global__ void gate_kernel(const float* __restrict__ g, const float* __restrict__ gw0,
                            const float* __restrict__ gb0, const float* __restrict__ gw1,
                            const float* __restrict__ gb1, float* __restrict__ cof) {
  int b = threadIdx.x;
  if (b >= 8) return;
  float lg[4], noise[4];
  for (int e = 0; e < 4; ++e) {
    float a0 = gb0[e], a1 = gb1[e];
    for (int c = 0; c < 64; ++c) {
      float gv = g[b * 64 + c];
      a0 += gv * gw0[e * 64 + c];
      a1 += gv * gw1[e * 64 + c];
    }
    lg[e] = a1 > 0.f ? a1 : 0.2f * a1;
    noise[e] = fmaxf(a0, 0.f) + log1pf(expf(-fabsf(a0)));
  }
  float nm = 0.25f * (noise[0] + noise[1] + noise[2] + noise[3]);
  float vs = 0.f;
  for (int e = 0; e < 4; ++e) { float d = noise[e] - nm; vs += d * d; }
  float ns = sqrtf(vs / 3.f);
  float sc[4];
  for (int e = 0; e < 4; ++e) sc[e] = lg[e] + (noise[e] - nm) / ns;
  int i1 = 0;
  for (int e = 1; e < 4; ++e) if (sc[e] > sc[i1]) i1 = e;
  int i2 = -1;
  for (int e = 0; e < 4; ++e) if (e != i1 && (i2 < 0 || sc[e] > sc[i2])) i2 = e;
  float mx = fmaxf(lg[i1], lg[i2]);
  float e1 = expf(lg[i1] - mx), e2 = expf(lg[i2] - mx);
  float d = e1 + e2;
  for (int e = 0; e < 4; ++e) cof[b * 4 + e] = 0.f;
  cof[b * 4 + i1] = e1 / d;
  cof[b * 4 + i2] = e2 / d;
}

// ---------- NHWC f32 acc -> NCHW f32 out ----------
__global__ __launch_bounds__(256) void nchw_kernel(const float* __restrict__ acc,
                                                   float* __restrict__ out) {
  int b = blockIdx.y, pix0 = blockIdx.x << 6, t = threadIdx.x;
  __shared__ float ts[64][68];
  for (int i = t; i < 1024; i += 256) {
    int px = i >> 4, grp = i & 15;
    f32x4 v = *(const f32x4*)(acc + ((size_t)b * HW2 + pix0 + px) * 64 + grp * 4);
    *(f32x4*)(&ts[px][grp * 4]) = v;
  }
  __syncthreads();
  int c = t >> 2, xg = t & 3;
#pragma unroll
  for (int j = 0; j < 4; ++j) {
    int px = xg * 16 + j * 4;
    f32x4 o;
#pragma unroll
    for (int k = 0; k < 4; ++k) o[k] = ts[px + k][c];
    *(f32x4*)(out + (((size_t)b * 64 + c) << 14) + pix0 + px) = o;
  }
}

extern "C" void kernel_launch(void* const* d_in, const int* in_sizes, int n_in,
                              void* d_out, int out_size, void* d_ws, size_t ws_size,
                              hipStream_t stream) {
  const float* x    = (const float*)d_in[0];
  const float* winv = (const float*)d_in[1];
  const float* w1   = (const float*)d_in[2];
  const float* b1   = (const float*)d_in[3];
  const float* nw   = (const float*)d_in[4];
  const float* nb   = (const float*)d_in[5];
  const float* w2   = (const float*)d_in[6];
  const float* b2   = (const float*)d_in[7];
  const float* fw   = (const float*)d_in[8];
  const float* fb   = (const float*)d_in[9];
  const float* gw0  = (const float*)d_in[10];
  const float* gb0  = (const float*)d_in[11];
  const float* gw1  = (const float*)d_in[12];
  const float* gb1  = (const float*)d_in[13];
  const float* ew1  = (const float*)d_in[14];
  const float* eb1  = (const float*)d_in[15];
  const float* ew2  = (const float*)d_in[16];
  const float* eb2  = (const float*)d_in[17];

  char* W = (char*)d_ws;
  ushort_t* A    = (ushort_t*)(W);               // 33.5MB: xhwc, then ycat [y1|y2]
  ushort_t* Bz   = (ushort_t*)(W + 33554432);    // 33.5MB: z [x1|x2]; later acc f32
  float*    accb = (float*)(W + 33554432);
  ushort_t* Ch   = (ushort_t*)(W + 67108864);    // 16.8MB: h / expert hidden
  ushort_t* Dx   = (ushort_t*)(W + 83886080);    // 16.8MB: E / xf
  ushort_t* w3   = (ushort_t*)(W + 100663296);   // [14][72][512] bf16 chunks
  ushort_t* wmm  = (ushort_t*)(W + 101695488);   // winv bf16 [128][128]
  ushort_t* wfu  = (ushort_t*)(W + 101728256);   // fuse bf16 [64][128]
  float* part1 = (float*)(W + 101744640);
  float* kh    = (float*)(W + 101810176);
  float* part2 = (float*)(W + 101812224);
  float* gbuf  = (float*)(W + 101943296);

  float* out = (float*)d_out;
  float* cof = out + (size_t)8 * 64 * HW2;

  const int WS3 = 36864;  // per-conv weight stride (ushorts)
  dim3 cg1(128, 8), cg3(64, 8), rg(32, 8);

  wtrans_kernel<<<2016, 256, 0, stream>>>(w1, w2, ew1, ew2, w3);
  cvt_kernel<<<64, 256, 0, stream>>>(winv, wmm, 16384);
  cvt_kernel<<<32, 256, 0, stream>>>(fw, wfu, 8192);
  xtrans_kernel<<<dim3(1024, 8), 256, 0, stream>>>(x, A);

  // z = winv @ x  (C=128 NHWC): x1=ch0-63, x2=ch64-127
  mm1_kernel<8><<<cg1, 256, 0, stream>>>(A, 128, wmm, nullptr, Bz, 128);

  // hin0(x2): y1 = x1 + x2 + conv2(inorm_half(conv1(x2)))
  conv3_kernel<M_PLAIN, false><<<cg3, 256, 0, stream>>>(Bz, 128, 64, w3 + 0 * WS3, b1,
      Ch, 64, 0, nullptr,0,0, nullptr,0,0, nullptr,0,0, kh, nullptr, 0);
  ireduce_kernel<<<rg, 256, 0, stream>>>(Ch, part1);
  istat_kernel<<<1, 256, 0, stream>>>(part1, nw, nb, kh);
  conv3_kernel<M_ADD2, true><<<cg3, 256, 0, stream>>>(Ch, 64, 0, w3 + 3 * WS3, b2,
      A, 128, 0, Bz, 128, 64, Bz, 128, 0, nullptr,0,0, kh, nullptr, 0);

  // hin2(y1): E = exp(0.8*(2*sigmoid(y1 + conv2(inorm_half(conv1(y1)))) - 1))
  conv3_kernel<M_PLAIN, false><<<cg3, 256, 0, stream>>>(A, 128, 0, w3 + 2 * WS3, b1 + 128,
      Ch, 64, 0, nullptr,0,0, nullptr,0,0, nullptr,0,0, kh, nullptr, 0);
  ireduce_kernel<<<rg, 256, 0, stream>>>(Ch, part1);
  istat_kernel<<<1, 256, 0, stream>>>(part1, nw + 64, nb + 64, kh);
  conv3_kernel<M_SIGEXP, true><<<cg3, 256, 0, stream>>>(Ch, 64, 0, w3 + 5 * WS3, b2 + 128,
      Dx, 64, 0, A, 128, 0, nullptr,0,0, nullptr,0,0, kh, nullptr, 0);

  // hin1(y1): y2 = x2*E + y1 + conv2(inorm_half(conv1(y1)))
  conv3_kernel<M_PLAIN, false><<<cg3, 256, 0, stream>>>(A, 128, 0, w3 + 1 * WS3, b1 + 64,
      Ch, 64, 0, nullptr,0,0, nullptr,0,0, nullptr,0,0, kh, nullptr, 0);
  ireduce_kernel<<<rg, 256, 0, stream>>>(Ch, part1);
  istat_kernel<<<1, 256, 0, stream>>>(part1, nw + 32, nb + 32, kh);
  conv3_kernel<M_COUPLE, true><<<cg3, 256, 0, stream>>>(Ch, 64, 0, w3 + 4 * WS3, b2 + 64,
      A, 128, 64, A, 128, 0, Bz, 128, 64, Dx, 64, 0, kh, nullptr, 0);

  // xf = fuse_w @ [y1;y2] + fb   (into Dx; E is dead)
  mm1_kernel<4><<<cg1, 256, 0, stream>>>(A, 128, wfu, fb, Dx, 64);

  // gating
  preduce_kernel<<<rg, 256, 0, stream>>>(Dx, part2);
  pool2_kernel<<<2, 256, 0, stream>>>(part2, gbuf);
  gate_kernel<<<1, 64, 0, stream>>>(gbuf, gw0, gb0, gw1, gb1, cof);

  // experts: acc(NHWC f32) = sum_e cof_e * (conv2(lrelu(conv1(xf))) + xf)
  for (int e = 0; e < 4; ++e) {
    conv3_kernel<M_LRELU, false><<<cg3, 256, 0, stream>>>(Dx, 64, 0, w3 + (6 + e) * WS3,
        eb1 + e * 64, Ch, 64, 0, nullptr,0,0, nullptr,0,0, nullptr,0,0, kh, cof, e);
    conv3_kernel<M_EACC, false><<<cg3, 256, 0, stream>>>(Ch, 64, 0, w3 + (10 + e) * WS3,
        eb2 + e * 64, (void*)accb, 64, 0, Dx, 64, 0, nullptr,0,0, nullptr,0,0, kh, cof, e);
  }

  nchw_kernel<<<dim3(256, 8), 256, 0, stream>>>(accb, out);
}